// Round 14
// baseline (138.717 us; speedup 1.0000x reference)
//
#include <hip/hip_runtime.h>

#define N_ROWS 8192
#define DIMS   256
#define NRT    128                     // 64-wide row tiles
#define NCT    64                      // 128-wide col tiles
#define NFULL  2048                    // 2-tile chunks: sum_ri floor((64-(ri>>1))/2)
#define NCHUNK 2112                    // + 64 single-tile leftovers (odd-length rows)
#define K1B    256                     // k1 blocks (32 rows = one plane rowblk each)
#define K3B    1024                    // k3 blocks (3 resident/CU) -> exactly 2 full chunks each

typedef _Float16 f16x4 __attribute__((ext_vector_type(4)));
typedef _Float16 f16x8 __attribute__((ext_vector_type(8)));
typedef float   f32x16 __attribute__((ext_vector_type(16)));

// ws layout:
// [0, 4MB)   : fp16 plane of x, MFMA-fragment-permuted
// [4MB,+32KB): float sq[8192]
// then       : colsumA[256] f32 | ssqA f32 | n0A u32 | Scalars{ctr,t3} | partial[K3B] f64
// (colsumA..Scalars = 1040 B zeroed by hipMemsetAsync EVERY launch -> replay-safe)
#define WS_PLANE  0
#define WS_SQ     (4 * 1024 * 1024)
#define WS_RED    (WS_SQ + 32768)
#define WS_SSQA   (WS_RED + 1024)
#define WS_N0A    (WS_SSQA + 4)
#define WS_SC     (WS_N0A + 4)
#define WS_PART   (WS_RED + 2048)

struct Scalars {
    unsigned int ctr;     // k3 chunk-queue head   (memset-zeroed each launch)
    unsigned int t3;      // k3 completion ticket  (memset-zeroed each launch)
};

// real asm load: cannot be sunk/split/rematerialized (r10-proven: holds preload)
#define BL(dst, p, o) asm volatile("global_load_dwordx4 %0, %1, off offset:" o \
                                   : "=v"(dst) : "v"(p))

// ---------------------------------------------------------------- K1: stats + fp16 plane (r12/r13-proven)
__global__ __launch_bounds__(256) void k1_rows(const float* __restrict__ x,
                                               const long long* __restrict__ sub,
                                               float* __restrict__ sq,
                                               float* __restrict__ colsumA,
                                               float* __restrict__ ssqA,
                                               unsigned int* __restrict__ n0A,
                                               unsigned short* __restrict__ plane) {
    __shared__ _Float16 stg[16 * 512];   // 16KB: permuted rowblk image
    __shared__ float cls[4][256];
    __shared__ float smq[4];
    const int t = threadIdx.x;
    const int l = t & 63;
    const int w = t >> 6;
    const int base = blockIdx.x * 32;

    float4 colacc = make_float4(0.f, 0.f, 0.f, 0.f);
    float  my_sumsq = 0.f;

    const int ks  = l >> 2;
    const int shi = ((l >> 1) & 1) * 32;
    const int j4  = (l & 1) * 4;

    #pragma unroll
    for (int r = 0; r < 8; ++r) {
        const int rr  = w * 8 + r;
        const int row = base + rr;
        const float4 v = ((const float4*)(x + (size_t)row * DIMS))[l];
        colacc.x += v.x; colacc.y += v.y; colacc.z += v.z; colacc.w += v.w;

        f16x4 h = { (_Float16)v.x, (_Float16)v.y, (_Float16)v.z, (_Float16)v.w };
        *(f16x4*)&stg[ks * 512 + (rr + shi) * 8 + j4] = h;

        float s = v.x * v.x + v.y * v.y + v.z * v.z + v.w * v.w;
        #pragma unroll
        for (int off = 32; off; off >>= 1) s += __shfl_down(s, off, 64);
        if (l == 0) { sq[row] = s; my_sumsq += s; }
    }
    if (l == 0) smq[w] = my_sumsq;
    *(float4*)&cls[w][l * 4] = colacc;
    __syncthreads();

    {
        const uint4* src = (const uint4*)stg;
        uint4* dst = (uint4*)(plane + (size_t)blockIdx.x * 8192);
        #pragma unroll
        for (int i = 0; i < 4; ++i) dst[i * 256 + t] = src[i * 256 + t];
    }

    atomicAdd(&colsumA[t], cls[0][t] + cls[1][t] + cls[2][t] + cls[3][t]);
    if (t == 0) atomicAdd(ssqA, smq[0] + smq[1] + smq[2] + smq[3]);
    if (w == 1) {
        unsigned long long m1 = __ballot(l < 32 && (int)sub[base + l] == 0);
        if (l == 0) atomicAdd(n0A, (unsigned int)__popcll(m1));
    }
}

// ---------------------------------------------------------------- K3: 64x128-tile balanced-queue MFMA Gram
// A-tile 64 rows x full-K = 32KB LDS (half of r13) -> ~162 total regs/wave
// (130 arch + 32 acc) -> 3 blocks/CU resident (r13: 192 regs -> 2/CU, Occ 16%).
// 4160 tiles; queue: q<2048 -> 2-tile chunk (exactly 2/block), q>=2048 ->
// single leftover (row with odd tile count, cj=63). Next ticket grabbed during
// the last tile's epilogue (atomic hidden). Wave w owns J-cols [cj*128+w*32,+32).
__global__ __launch_bounds__(256, 2) void k3_mmd(const unsigned short* __restrict__ plane,
                                                 const long long* __restrict__ sub,
                                                 const float* __restrict__ sq,
                                                 const float* __restrict__ colsumA,
                                                 const float* __restrict__ ssqA,
                                                 const unsigned int* __restrict__ n0A,
                                                 Scalars* sc,
                                                 double* __restrict__ partial,
                                                 float* __restrict__ out) {
    __shared__ char ldsA[32768];
    __shared__ float2 sqwI[64];
    __shared__ double dd[4];
    __shared__ unsigned int qb;

    const int t  = threadIdx.x;
    const int l  = t & 63;
    const int w  = t >> 6;        // wave = J-column group (1x4 wave grid)
    const int lh = l >> 5;
    const int ln = l & 31;

    // ---- scalar prologue (redundant per block, no barrier): ~300 cy
    float c2, w0, w1;
    {
        const float4 c4 = ((const float4*)colsumA)[l];
        float cs2 = c4.x * c4.x + c4.y * c4.y + c4.z * c4.z + c4.w * c4.w;
        #pragma unroll
        for (int off = 32; off; off >>= 1) cs2 += __shfl_xor(cs2, off, 64);
        const float ssq = *ssqA;
        const float n0f = (float)*n0A;
        const double n = (double)N_ROWS;
        const double sumL2 = 2.0 * n * (double)ssq - 2.0 * (double)cs2;
        const double bw = sumL2 / (n * n - n) / 4.0;   // / KERNEL_MUL^(KERNEL_NUM/2)
        c2 = (float)(-1.4426950408889634 / (16.0 * bw));
        const double n0 = (double)n0f, n1 = n - n0;
        w0 = (float)( 1.0 / n0);
        w1 = (float)(-1.0 / n1);
    }

    double dsum = 0.0;
    f16x8 b[16];

    if (t == 0) qb = atomicAdd(&sc->ctr, 1u);
    for (;;) {
        __syncthreads();                       // qb visible + A safe from prev readers
        const unsigned q0 = qb;
        if (q0 >= NCHUNK) break;               // uniform exit
        int ri, cj, nt;
        if (q0 < NFULL) {                      // 2-tile chunk
            int q = (int)q0; ri = 0;
            for (;;) { const int fc = (NCT - (ri >> 1)) >> 1; if (q < fc) break; q -= fc; ++ri; }
            cj = (ri >> 1) + 2 * q;
            nt = 2;
        } else {                               // leftover: odd-count row, last col tile
            const int s = (int)(q0 - NFULL);   // 0..63
            const int bb = 2 * (s >> 1) + 1;
            ri = 2 * bb + (s & 1);
            cj = NCT - 1;
            nt = 1;
        }

        // ---- stage A (64 rows x full K = 32 x 1KB regions, 8 per wave)
        #pragma unroll
        for (int i = 0; i < 8; ++i) {
            const unsigned short* g = plane + (((size_t)(ri * 32 + w * 8 + i)) << 9) + (l << 3);
            char* lp = ldsA + ((w * 8 + i) << 10);
            __builtin_amdgcn_global_load_lds(
                (const __attribute__((address_space(1))) unsigned int*)(const void*)g,
                (__attribute__((address_space(3))) unsigned int*)(void*)lp, 16, 0, 0);
        }
        // ---- I-side (sq, weight) once per chunk
        if (t < 64) {
            const int I = ri * 64 + t;
            sqwI[t] = make_float2(sq[I], ((int)sub[I] == 0) ? w0 : w1);
        }
        // ---- first tile's B via asm loads (ride the same drain window)
        {
            const unsigned short* p0 = plane + (((size_t)(cj * 4 + w) * 16) << 9) + (l << 3);
            const unsigned short* p1 = p0 + 2048;
            const unsigned short* p2 = p0 + 4096;
            const unsigned short* p3 = p0 + 6144;
            BL(b[0], p0,"0"); BL(b[1], p0,"1024"); BL(b[2], p0,"2048"); BL(b[3], p0,"3072");
            BL(b[4], p1,"0"); BL(b[5], p1,"1024"); BL(b[6], p1,"2048"); BL(b[7], p1,"3072");
            BL(b[8], p2,"0"); BL(b[9], p2,"1024"); BL(b[10],p2,"2048"); BL(b[11],p2,"3072");
            BL(b[12],p3,"0"); BL(b[13],p3,"1024"); BL(b[14],p3,"2048"); BL(b[15],p3,"3072");
        }
        const int J0 = cj * 128 + w * 32 + ln;
        float sJ  = sq[J0];
        float wJv = ((int)sub[J0] == 0) ? w0 : w1;
        __syncthreads();                       // ONE drain: A-DMA + B + sqwI

        for (int tt = 0; tt < nt; ++tt) {
            const int cjt = cj + tt;
            const bool dg = (cjt == (ri >> 1));       // tile touches the diagonal
            asm volatile("s_waitcnt vmcnt(0)" ::: "memory");  // B (+prefetch) landed
            __builtin_amdgcn_sched_barrier(0);                // rule #18: no hoisting

            f32x16 acc[2] = {};
            #pragma unroll
            for (int ks = 0; ks < 16; ++ks) {
                #pragma unroll
                for (int m = 0; m < 2; ++m) {
                    const f16x8 a = *(const f16x8*)(ldsA + ((m * 16 + ks) << 10) + (l << 4));
                    acc[m] = __builtin_amdgcn_mfma_f32_32x32x16_f16(a, b[ks], acc[m], 0, 0, 0);
                }
            }

            // ---- grab NEXT chunk's ticket during last tile (latency hidden)
            if (tt == nt - 1 && t == 0) qb = atomicAdd(&sc->ctr, 1u);

            // ---- prefetch next tile's B + scalars (fly under the epilogue)
            float sJn = 0.f, wJn = 0.f;
            if (tt + 1 < nt) {
                const unsigned short* p0 = plane + (((size_t)((cjt + 1) * 4 + w) * 16) << 9) + (l << 3);
                const unsigned short* p1 = p0 + 2048;
                const unsigned short* p2 = p0 + 4096;
                const unsigned short* p3 = p0 + 6144;
                BL(b[0], p0,"0"); BL(b[1], p0,"1024"); BL(b[2], p0,"2048"); BL(b[3], p0,"3072");
                BL(b[4], p1,"0"); BL(b[5], p1,"1024"); BL(b[6], p1,"2048"); BL(b[7], p1,"3072");
                BL(b[8], p2,"0"); BL(b[9], p2,"1024"); BL(b[10],p2,"2048"); BL(b[11],p2,"3072");
                BL(b[12],p3,"0"); BL(b[13],p3,"1024"); BL(b[14],p3,"2048"); BL(b[15],p3,"3072");
                const int Jn = (cjt + 1) * 128 + w * 32 + ln;
                sJn = sq[Jn];
                wJn = ((int)sub[Jn] == 0) ? w0 : w1;
            }

            // ---- epilogue: L2 -> multi-scale kernel -> weighted partial sum
            float part = 0.f;
            #pragma unroll
            for (int m = 0; m < 2; ++m) {
                #pragma unroll
                for (int r = 0; r < 16; ++r) {
                    // C/D layout: col = lane&31, row = (r&3) + 8*(r>>2) + 4*(lane>>5)
                    const int Il = m * 32 + (r & 3) + ((r >> 2) << 3) + (lh << 2);
                    const float2 pi = sqwI[Il];
                    float l2 = fmaxf(pi.x + sJ - 2.f * acc[m][r], 0.f);
                    const float e  = __builtin_amdgcn_exp2f(l2 * c2);
                    const float e2 = e * e, e4 = e2 * e2, e8 = e4 * e4;
                    const float K  = ((e + e2) + (e4 + e8)) + e8 * e8;
                    float w2 = pi.y * wJv;
                    if (dg) {
                        const int Ig = ri * 64 + Il;
                        const int Jg = cjt * 128 + w * 32 + ln;
                        w2 *= (Ig < Jg) ? 2.f : ((Ig == Jg) ? 1.f : 0.f);
                    }
                    part = fmaf(K, w2, part);
                }
            }
            dsum += (double)part * (dg ? 1.0 : 2.0);
            sJ = sJn; wJv = wJn;
        }
    }

    // ---- block reduce -> partial[bid]; last block reduces all -> out
    #pragma unroll
    for (int off = 32; off; off >>= 1) dsum += __shfl_down(dsum, off, 64);
    __syncthreads();
    if (l == 0) dd[w] = dsum;
    __syncthreads();
    if (t == 0) {
        partial[blockIdx.x] = dd[0] + dd[1] + dd[2] + dd[3];
        __threadfence();       // release: partial visible before ticket bump
        qb = (atomicAdd(&sc->t3, 1u) == K3B - 1) ? 1u : 0u;
    }
    __syncthreads();
    if (qb) {                  // block-uniform last-block flag
        __threadfence();       // acquire: see all producers' partials
        double v = partial[t] + partial[t + 256] + partial[t + 512] + partial[t + 768];
        #pragma unroll
        for (int off = 32; off; off >>= 1) v += __shfl_down(v, off, 64);
        if (l == 0) dd[w] = v;
        __syncthreads();
        if (t == 0) out[0] = (float)(dd[0] + dd[1] + dd[2] + dd[3]);
    }
}

extern "C" void kernel_launch(void* const* d_in, const int* in_sizes, int n_in,
                              void* d_out, int out_size, void* d_ws, size_t ws_size,
                              hipStream_t stream) {
    const long long* sub = (const long long*)d_in[0];   // subggroup int64 (N,1)
    const float*     x   = (const float*)d_in[1];       // outputs fp32 (N,256)
    float* out = (float*)d_out;

    char* ws = (char*)d_ws;
    unsigned short* plane   = (unsigned short*)(ws + WS_PLANE);
    float*          sq      = (float*)(ws + WS_SQ);
    float*          colsumA = (float*)(ws + WS_RED);
    float*          ssqA    = (float*)(ws + WS_SSQA);
    unsigned int*   n0A     = (unsigned int*)(ws + WS_N0A);
    Scalars*        sc      = (Scalars*)(ws + WS_SC);
    double*         partial = (double*)(ws + WS_PART);

    // zero accumulators + queue + ticket (1040B) — re-established EVERY launch
    hipMemsetAsync(ws + WS_RED, 0, 1040, stream);
    k1_rows<<<K1B, 256, 0, stream>>>(x, sub, sq, colsumA, ssqA, n0A, plane);
    k3_mmd<<<K3B, 256, 0, stream>>>(plane, sub, sq, colsumA, ssqA, n0A, sc, partial, out);
}

// Round 15
// 115.376 us; speedup vs baseline: 1.2023x; 1.2023x over previous
//
#include <hip/hip_runtime.h>

#define N_ROWS 8192
#define DIMS   256
#define NTILE  64                      // 8192 / 128
#define NFULL  1024                    // full 2-tile chunks: sum floor((64-bi)/2)
#define NCHUNK 1056                    // + 32 single-tile leftovers (rows with odd length)
#define K1B    256                     // k1 blocks (32 rows = one plane rowblk each)
#define K3B    512                     // k3 blocks (2 per CU) -> exactly 2 full chunks each

typedef _Float16 f16x4 __attribute__((ext_vector_type(4)));
typedef _Float16 f16x8 __attribute__((ext_vector_type(8)));
typedef float   f32x16 __attribute__((ext_vector_type(16)));

// ws layout:
// [0, 4MB)   : fp16 plane of x, MFMA-fragment-permuted
// [4MB,+32KB): float sq[8192]
// then       : colsumA[256] f32 | ssqA f32 | n0A u32 | Scalars{ctr,t3} | partial[K3B] f64
// (colsumA..Scalars = 1040 B zeroed by hipMemsetAsync EVERY launch -> replay-safe)
#define WS_PLANE  0
#define WS_SQ     (4 * 1024 * 1024)
#define WS_RED    (WS_SQ + 32768)
#define WS_SSQA   (WS_RED + 1024)
#define WS_N0A    (WS_SSQA + 4)
#define WS_SC     (WS_N0A + 4)
#define WS_PART   (WS_RED + 2048)

struct Scalars {
    unsigned int ctr;     // k3 chunk-queue head   (memset-zeroed each launch)
    unsigned int t3;      // k3 completion ticket  (memset-zeroed each launch)
};

// real asm load: cannot be sunk/split/rematerialized (r10-proven: holds preload)
#define BL(dst, p, o) asm volatile("global_load_dwordx4 %0, %1, off offset:" o \
                                   : "=v"(dst) : "v"(p))

// ---------------------------------------------------------------- K1: stats + fp16 plane (r12/r13-proven)
__global__ __launch_bounds__(256) void k1_rows(const float* __restrict__ x,
                                               const long long* __restrict__ sub,
                                               float* __restrict__ sq,
                                               float* __restrict__ colsumA,
                                               float* __restrict__ ssqA,
                                               unsigned int* __restrict__ n0A,
                                               unsigned short* __restrict__ plane) {
    __shared__ _Float16 stg[16 * 512];   // 16KB: permuted rowblk image
    __shared__ float cls[4][256];
    __shared__ float smq[4];
    const int t = threadIdx.x;
    const int l = t & 63;
    const int w = t >> 6;
    const int base = blockIdx.x * 32;

    float4 colacc = make_float4(0.f, 0.f, 0.f, 0.f);
    float  my_sumsq = 0.f;

    const int ks  = l >> 2;
    const int shi = ((l >> 1) & 1) * 32;
    const int j4  = (l & 1) * 4;

    #pragma unroll
    for (int r = 0; r < 8; ++r) {
        const int rr  = w * 8 + r;
        const int row = base + rr;
        const float4 v = ((const float4*)(x + (size_t)row * DIMS))[l];
        colacc.x += v.x; colacc.y += v.y; colacc.z += v.z; colacc.w += v.w;

        f16x4 h = { (_Float16)v.x, (_Float16)v.y, (_Float16)v.z, (_Float16)v.w };
        *(f16x4*)&stg[ks * 512 + (rr + shi) * 8 + j4] = h;

        float s = v.x * v.x + v.y * v.y + v.z * v.z + v.w * v.w;
        #pragma unroll
        for (int off = 32; off; off >>= 1) s += __shfl_down(s, off, 64);
        if (l == 0) { sq[row] = s; my_sumsq += s; }
    }
    if (l == 0) smq[w] = my_sumsq;
    *(float4*)&cls[w][l * 4] = colacc;
    __syncthreads();

    {
        const uint4* src = (const uint4*)stg;
        uint4* dst = (uint4*)(plane + (size_t)blockIdx.x * 8192);
        #pragma unroll
        for (int i = 0; i < 4; ++i) dst[i * 256 + t] = src[i * 256 + t];
    }

    atomicAdd(&colsumA[t], cls[0][t] + cls[1][t] + cls[2][t] + cls[3][t]);
    if (t == 0) atomicAdd(ssqA, smq[0] + smq[1] + smq[2] + smq[3]);
    if (w == 1) {
        unsigned long long m1 = __ballot(l < 32 && (int)sub[base + l] == 0);
        if (l == 0) atomicAdd(n0A, (unsigned int)__popcll(m1));
    }
}

// ---------------------------------------------------------------- K3: balanced-queue MFMA Gram (r13 base)
// 128x128 tiles, 2-tile chunks (exactly 2/block over 512 blocks, tiny tail).
// NEW vs r13: (1) A-fragment ds_reads software-pipelined one ks-stage ahead in
// named registers — r13's read-then-MFMA chain exposed ~120cy LDS latency per
// fragment with only 2 waves/SIMD of TLP (the ~9k cy/tile stall in the budget);
// (2) next chunk's ticket grabbed during the last tile's epilogue (r14's trick).
__global__ __launch_bounds__(256, 2) void k3_mmd(const unsigned short* __restrict__ plane,
                                                 const long long* __restrict__ sub,
                                                 const float* __restrict__ sq,
                                                 const float* __restrict__ colsumA,
                                                 const float* __restrict__ ssqA,
                                                 const unsigned int* __restrict__ n0A,
                                                 Scalars* sc,
                                                 double* __restrict__ partial,
                                                 float* __restrict__ out) {
    __shared__ char ldsA[65536];
    __shared__ float2 sqwI[128];
    __shared__ double dd[4];
    __shared__ unsigned int qb;

    const int t  = threadIdx.x;
    const int l  = t & 63;
    const int w  = t >> 6;        // wave = J-column group (1x4 wave grid)
    const int lh = l >> 5;
    const int ln = l & 31;

    // ---- scalar prologue (redundant per block, no barrier): ~300 cy
    float c2, w0, w1;
    {
        const float4 c4 = ((const float4*)colsumA)[l];
        float cs2 = c4.x * c4.x + c4.y * c4.y + c4.z * c4.z + c4.w * c4.w;
        #pragma unroll
        for (int off = 32; off; off >>= 1) cs2 += __shfl_xor(cs2, off, 64);
        const float ssq = *ssqA;
        const float n0f = (float)*n0A;
        const double n = (double)N_ROWS;
        const double sumL2 = 2.0 * n * (double)ssq - 2.0 * (double)cs2;
        const double bw = sumL2 / (n * n - n) / 4.0;   // / KERNEL_MUL^(KERNEL_NUM/2)
        c2 = (float)(-1.4426950408889634 / (16.0 * bw));
        const double n0 = (double)n0f, n1 = n - n0;
        w0 = (float)( 1.0 / n0);
        w1 = (float)(-1.0 / n1);
    }

    double dsum = 0.0;
    f16x8 b[16];

    if (t == 0) qb = atomicAdd(&sc->ctr, 1u);
    for (;;) {
        __syncthreads();                       // qb visible + A safe from prev readers
        const unsigned q0 = qb;
        if (q0 >= NCHUNK) break;               // uniform exit
        int bi, bj, nt;
        if (q0 < NFULL) {                      // 2-tile chunk
            int q = (int)q0; bi = 0;
            while (q >= ((NTILE - bi) >> 1)) { q -= (NTILE - bi) >> 1; ++bi; }
            bj = bi + q * 2;
            nt = 2;
        } else {                               // single leftover: odd-length row, last tile
            bi = 2 * (int)(q0 - NFULL) + 1;
            bj = NTILE - 1;
            nt = 1;
        }

        // ---- stage A full-K: wave w stages rowblk bi*4+w (16 x 1KB regions)
        #pragma unroll
        for (int i = 0; i < 16; ++i) {
            const unsigned short* g = plane + (((size_t)(bi * 4 + w) * 16 + i) << 9) + (l << 3);
            char* lp = ldsA + ((w * 16 + i) << 10);
            __builtin_amdgcn_global_load_lds(
                (const __attribute__((address_space(1))) unsigned int*)(const void*)g,
                (__attribute__((address_space(3))) unsigned int*)(void*)lp, 16, 0, 0);
        }
        // ---- stage I-side (sq, weight) once per chunk
        if (t < 128) {
            const int I = bi * 128 + t;
            sqwI[t] = make_float2(sq[I], ((int)sub[I] == 0) ? w0 : w1);
        }
        // ---- first tile's B via asm loads (ride the same drain window)
        {
            const unsigned short* p0 = plane + (((size_t)(bj * 4 + w) * 16) << 9) + (l << 3);
            const unsigned short* p1 = p0 + 2048;
            const unsigned short* p2 = p0 + 4096;
            const unsigned short* p3 = p0 + 6144;
            BL(b[0], p0,"0"); BL(b[1], p0,"1024"); BL(b[2], p0,"2048"); BL(b[3], p0,"3072");
            BL(b[4], p1,"0"); BL(b[5], p1,"1024"); BL(b[6], p1,"2048"); BL(b[7], p1,"3072");
            BL(b[8], p2,"0"); BL(b[9], p2,"1024"); BL(b[10],p2,"2048"); BL(b[11],p2,"3072");
            BL(b[12],p3,"0"); BL(b[13],p3,"1024"); BL(b[14],p3,"2048"); BL(b[15],p3,"3072");
        }
        const int J0 = bj * 128 + w * 32 + ln;
        float sJ  = sq[J0];
        float wJv = ((int)sub[J0] == 0) ? w0 : w1;
        __syncthreads();                       // ONE drain: A-DMA + B + sqwI

        for (int tt = 0; tt < nt; ++tt, ++bj) {
            const bool dg = (bj == bi);
            asm volatile("s_waitcnt vmcnt(0)" ::: "memory");  // B (+prefetch) landed
            __builtin_amdgcn_sched_barrier(0);                // rule #18: no hoisting

            // ---- MFMA loop, A-frags pipelined one ks-stage ahead (ILP fix)
            f32x16 acc[4] = {};
            f16x8 a0, a1, a2, a3, x0, x1, x2, x3;
            a0 = *(const f16x8*)(ldsA + (( 0 * 16 + 0) << 10) + (l << 4));
            a1 = *(const f16x8*)(ldsA + (( 1 * 16 + 0) << 10) + (l << 4));
            a2 = *(const f16x8*)(ldsA + (( 2 * 16 + 0) << 10) + (l << 4));
            a3 = *(const f16x8*)(ldsA + (( 3 * 16 + 0) << 10) + (l << 4));
            #pragma unroll
            for (int ks = 0; ks < 16; ++ks) {
                if (ks < 15) {
                    x0 = *(const f16x8*)(ldsA + ((0 * 16 + ks + 1) << 10) + (l << 4));
                    x1 = *(const f16x8*)(ldsA + ((1 * 16 + ks + 1) << 10) + (l << 4));
                    x2 = *(const f16x8*)(ldsA + ((2 * 16 + ks + 1) << 10) + (l << 4));
                    x3 = *(const f16x8*)(ldsA + ((3 * 16 + ks + 1) << 10) + (l << 4));
                }
                acc[0] = __builtin_amdgcn_mfma_f32_32x32x16_f16(a0, b[ks], acc[0], 0, 0, 0);
                acc[1] = __builtin_amdgcn_mfma_f32_32x32x16_f16(a1, b[ks], acc[1], 0, 0, 0);
                acc[2] = __builtin_amdgcn_mfma_f32_32x32x16_f16(a2, b[ks], acc[2], 0, 0, 0);
                acc[3] = __builtin_amdgcn_mfma_f32_32x32x16_f16(a3, b[ks], acc[3], 0, 0, 0);
                a0 = x0; a1 = x1; a2 = x2; a3 = x3;
            }

            // ---- last tile: grab NEXT chunk's ticket (atomic hidden under epilogue)
            if (tt == nt - 1 && t == 0) qb = atomicAdd(&sc->ctr, 1u);

            // ---- prefetch next tile's B + scalars (fly under the epilogue)
            float sJn = 0.f, wJn = 0.f;
            if (tt + 1 < nt) {
                const unsigned short* p0 = plane + (((size_t)((bj + 1) * 4 + w) * 16) << 9) + (l << 3);
                const unsigned short* p1 = p0 + 2048;
                const unsigned short* p2 = p0 + 4096;
                const unsigned short* p3 = p0 + 6144;
                BL(b[0], p0,"0"); BL(b[1], p0,"1024"); BL(b[2], p0,"2048"); BL(b[3], p0,"3072");
                BL(b[4], p1,"0"); BL(b[5], p1,"1024"); BL(b[6], p1,"2048"); BL(b[7], p1,"3072");
                BL(b[8], p2,"0"); BL(b[9], p2,"1024"); BL(b[10],p2,"2048"); BL(b[11],p2,"3072");
                BL(b[12],p3,"0"); BL(b[13],p3,"1024"); BL(b[14],p3,"2048"); BL(b[15],p3,"3072");
                const int Jn = (bj + 1) * 128 + w * 32 + ln;
                sJn = sq[Jn];
                wJn = ((int)sub[Jn] == 0) ? w0 : w1;
            }

            // ---- epilogue: L2 -> multi-scale kernel -> weighted partial sum
            float part = 0.f;
            #pragma unroll
            for (int m = 0; m < 4; ++m) {
                #pragma unroll
                for (int r = 0; r < 16; ++r) {
                    // C/D layout: col = lane&31, row = (r&3) + 8*(r>>2) + 4*(lane>>5)
                    const int Il = m * 32 + (r & 3) + ((r >> 2) << 3) + (lh << 2);
                    const float2 pi = sqwI[Il];
                    float l2 = fmaxf(pi.x + sJ - 2.f * acc[m][r], 0.f);
                    const float e  = __builtin_amdgcn_exp2f(l2 * c2);
                    const float e2 = e * e, e4 = e2 * e2, e8 = e4 * e4;
                    const float K  = ((e + e2) + (e4 + e8)) + e8 * e8;
                    float w2 = pi.y * wJv;
                    if (dg) {
                        const int Jl = w * 32 + ln;
                        w2 *= (Il < Jl) ? 2.f : ((Il == Jl) ? 1.f : 0.f);
                    }
                    part = fmaf(K, w2, part);
                }
            }
            dsum += (double)part * (dg ? 1.0 : 2.0);
            sJ = sJn; wJv = wJn;
        }
    }

    // ---- block reduce -> partial[bid]; last block reduces all -> out
    #pragma unroll
    for (int off = 32; off; off >>= 1) dsum += __shfl_down(dsum, off, 64);
    __syncthreads();
    if (l == 0) dd[w] = dsum;
    __syncthreads();
    if (t == 0) {
        partial[blockIdx.x] = dd[0] + dd[1] + dd[2] + dd[3];
        __threadfence();       // release: partial visible before ticket bump
        qb = (atomicAdd(&sc->t3, 1u) == K3B - 1) ? 1u : 0u;
    }
    __syncthreads();
    if (qb) {                  // block-uniform last-block flag
        __threadfence();       // acquire: see all producers' partials
        double v = partial[t] + partial[t + 256];
        #pragma unroll
        for (int off = 32; off; off >>= 1) v += __shfl_down(v, off, 64);
        if (l == 0) dd[w] = v;
        __syncthreads();
        if (t == 0) out[0] = (float)(dd[0] + dd[1] + dd[2] + dd[3]);
    }
}

extern "C" void kernel_launch(void* const* d_in, const int* in_sizes, int n_in,
                              void* d_out, int out_size, void* d_ws, size_t ws_size,
                              hipStream_t stream) {
    const long long* sub = (const long long*)d_in[0];   // subggroup int64 (N,1)
    const float*     x   = (const float*)d_in[1];       // outputs fp32 (N,256)
    float* out = (float*)d_out;

    char* ws = (char*)d_ws;
    unsigned short* plane   = (unsigned short*)(ws + WS_PLANE);
    float*          sq      = (float*)(ws + WS_SQ);
    float*          colsumA = (float*)(ws + WS_RED);
    float*          ssqA    = (float*)(ws + WS_SSQA);
    unsigned int*   n0A     = (unsigned int*)(ws + WS_N0A);
    Scalars*        sc      = (Scalars*)(ws + WS_SC);
    double*         partial = (double*)(ws + WS_PART);

    // zero accumulators + queue + ticket (1040B) — re-established EVERY launch
    hipMemsetAsync(ws + WS_RED, 0, 1040, stream);
    k1_rows<<<K1B, 256, 0, stream>>>(x, sub, sq, colsumA, ssqA, n0A, plane);
    k3_mmd<<<K3B, 256, 0, stream>>>(plane, sub, sq, colsumA, ssqA, n0A, sc, partial, out);
}